// Round 2
// baseline (256.039 us; speedup 1.0000x reference)
//
#include <hip/hip_runtime.h>

// Lowpass IIR scan: level[t] = (1-s)*x[t] + s*level[t-1], s = sigmoid(smooth).
// Two-kernel chunked-scan decomposition (cooperative launch does NOT work in
// this harness -> fell back from fused version), float4-vectorized:
//   K1: per-chunk partial finals P_c (zero-entry scan), pure streaming read.
//   K2: entry_c = P_{c-1} + s^L * entry_{c-1} recombined in-register,
//       then scan + store chunk with non-temporal stores (keep input in L3).
// float4 per lane -> each wave moves 1 KB contiguous per step.

typedef float f32x4 __attribute__((ext_vector_type(4)));

constexpr int B   = 16;
constexpr int T   = 2048;
constexpr int U   = 1024;
constexpr int U4  = U / 4;        // 256 float4 per row
constexpr int BU4 = B * U4;       // 4096 chain-groups (power of 2)

__device__ __forceinline__ float sigmoidf(float x) {
    return 1.0f / (1.0f + __expf(-x));
}

// ---- Kernel 1: per-chunk partial finals P[c][chain-group] ----
template <int C>
__global__ __launch_bounds__(64) void lowpass_partial(
    const f32x4* __restrict__ in,      // [B*T*U4]
    const float* __restrict__ smooth,  // [U]
    f32x4*       __restrict__ P)       // [C*BU4]
{
    constexpr int L  = T / C;
    constexpr int D1 = 16;             // prefetch depth (loads only)
    static_assert(L > D1 && L % D1 == 0, "prefetch");

    const int tid = blockIdx.x * 64 + (int)threadIdx.x;
    const int c   = tid >> 12;             // chunk (BU4 = 2^12)
    const int lg  = tid & (BU4 - 1);
    const int b   = lg >> 8;               // U4 = 2^8
    const int ug  = lg & (U4 - 1);

    const f32x4 sm = reinterpret_cast<const f32x4*>(smooth)[ug];
    const float s0 = sigmoidf(sm.x), s1 = sigmoidf(sm.y),
                s2 = sigmoidf(sm.z), s3 = sigmoidf(sm.w);
    const float o0 = 1.0f - s0, o1 = 1.0f - s1,
                o2 = 1.0f - s2, o3 = 1.0f - s3;

    const f32x4* __restrict__ ip = in + (b * T + c * L) * U4 + ug;

    float a0 = 0.0f, a1 = 0.0f, a2 = 0.0f, a3 = 0.0f;
    f32x4 buf[D1];
    #pragma unroll
    for (int i = 0; i < D1; ++i) buf[i] = ip[i * U4];

    int t = 0;
    for (; t < L - D1; t += D1) {
        #pragma unroll
        for (int j = 0; j < D1; ++j) {
            f32x4 x = buf[j];
            buf[j] = ip[(t + D1 + j) * U4];
            a0 = fmaf(s0, a0, o0 * x.x);
            a1 = fmaf(s1, a1, o1 * x.y);
            a2 = fmaf(s2, a2, o2 * x.z);
            a3 = fmaf(s3, a3, o3 * x.w);
        }
    }
    #pragma unroll
    for (int j = 0; j < D1; ++j) {
        f32x4 x = buf[j];
        a0 = fmaf(s0, a0, o0 * x.x);
        a1 = fmaf(s1, a1, o1 * x.y);
        a2 = fmaf(s2, a2, o2 * x.z);
        a3 = fmaf(s3, a3, o3 * x.w);
    }
    f32x4 part; part.x = a0; part.y = a1; part.z = a2; part.w = a3;
    P[c * BU4 + lg] = part;
}

// ---- Kernel 2: recombine entry level, scan chunk, store ----
template <int C>
__global__ __launch_bounds__(64) void lowpass_scan(
    const f32x4* __restrict__ in,      // [B*T*U4]
    const float* __restrict__ level0,  // [U]
    const float* __restrict__ smooth,  // [U]
    const f32x4* __restrict__ P,       // [C*BU4]
    f32x4*       __restrict__ out)     // [B*T*U4]
{
    constexpr int L    = T / C;
    constexpr int D2   = 8;            // prefetch depth (loads+stores share vmcnt)
    constexpr int LOG2L = 31 - __builtin_clz(L);
    static_assert(L > D2 && L % D2 == 0, "prefetch");
    static_assert((1 << LOG2L) == L, "pow2");

    const int tid = blockIdx.x * 64 + (int)threadIdx.x;
    const int c   = tid >> 12;
    const int lg  = tid & (BU4 - 1);
    const int b   = lg >> 8;
    const int ug  = lg & (U4 - 1);

    const f32x4 sm = reinterpret_cast<const f32x4*>(smooth)[ug];
    const float s0 = sigmoidf(sm.x), s1 = sigmoidf(sm.y),
                s2 = sigmoidf(sm.z), s3 = sigmoidf(sm.w);
    const float o0 = 1.0f - s0, o1 = 1.0f - s1,
                o2 = 1.0f - s2, o3 = 1.0f - s3;

    // s^L via repeated squaring
    float sL0 = s0, sL1 = s1, sL2 = s2, sL3 = s3;
    #pragma unroll
    for (int i = 0; i < LOG2L; ++i) {
        sL0 *= sL0; sL1 *= sL1; sL2 *= sL2; sL3 *= sL3;
    }

    const f32x4 l0 = reinterpret_cast<const f32x4*>(level0)[ug];
    float v0 = l0.x, v1 = l0.y, v2 = l0.z, v3 = l0.w;
    for (int i = 0; i < c; ++i) {          // uniform trip count per block
        f32x4 p = P[i * BU4 + lg];
        v0 = fmaf(sL0, v0, p.x);
        v1 = fmaf(sL1, v1, p.y);
        v2 = fmaf(sL2, v2, p.z);
        v3 = fmaf(sL3, v3, p.w);
    }

    const int base = (b * T + c * L) * U4 + ug;
    const f32x4* __restrict__ ip = in  + base;
    f32x4*       __restrict__ op = out + base;

    f32x4 buf[D2];
    #pragma unroll
    for (int i = 0; i < D2; ++i) buf[i] = ip[i * U4];

    int t = 0;
    for (; t < L - D2; t += D2) {
        #pragma unroll
        for (int j = 0; j < D2; ++j) {
            f32x4 x = buf[j];
            buf[j] = ip[(t + D2 + j) * U4];
            v0 = fmaf(s0, v0, o0 * x.x);
            v1 = fmaf(s1, v1, o1 * x.y);
            v2 = fmaf(s2, v2, o2 * x.z);
            v3 = fmaf(s3, v3, o3 * x.w);
            f32x4 r; r.x = v0; r.y = v1; r.z = v2; r.w = v3;
            __builtin_nontemporal_store(r, &op[(t + j) * U4]);
        }
    }
    #pragma unroll
    for (int j = 0; j < D2; ++j) {
        f32x4 x = buf[j];
        v0 = fmaf(s0, v0, o0 * x.x);
        v1 = fmaf(s1, v1, o1 * x.y);
        v2 = fmaf(s2, v2, o2 * x.z);
        v3 = fmaf(s3, v3, o3 * x.w);
        f32x4 r; r.x = v0; r.y = v1; r.z = v2; r.w = v3;
        __builtin_nontemporal_store(r, &op[(t + j) * U4]);
    }
}

extern "C" void kernel_launch(void* const* d_in, const int* in_sizes, int n_in,
                              void* d_out, int out_size, void* d_ws, size_t ws_size,
                              hipStream_t stream) {
    const f32x4* in     = (const f32x4*)d_in[0];  // inputs [B,T,U]
    const float* level0 = (const float*)d_in[1];  // level_var [1,U]
    const float* smooth = (const float*)d_in[2];  // smoothing_var [1,U]
    f32x4* out          = (f32x4*)d_out;
    f32x4* P            = (f32x4*)d_ws;

    dim3 block(64);
    // Prefer C=16 (1 MiB workspace, 1024 waves = 4/CU); fall back to C=8
    // (512 KiB, known-safe from prior session) if the workspace is small.
    if (ws_size >= (size_t)16 * BU4 * sizeof(f32x4)) {
        constexpr int C = 16;
        dim3 grid(C * BU4 / 64);   // 1024 blocks
        hipLaunchKernelGGL(lowpass_partial<C>, grid, block, 0, stream, in, smooth, P);
        hipLaunchKernelGGL(lowpass_scan<C>,    grid, block, 0, stream, in, level0, smooth, P, out);
    } else {
        constexpr int C = 8;
        dim3 grid(C * BU4 / 64);   // 512 blocks
        hipLaunchKernelGGL(lowpass_partial<C>, grid, block, 0, stream, in, smooth, P);
        hipLaunchKernelGGL(lowpass_scan<C>,    grid, block, 0, stream, in, level0, smooth, P, out);
    }
}